// Round 19
// baseline (66.059 us; speedup 1.0000x reference)
//
#include <hip/hip_runtime.h>
#include <hip/hip_fp16.h>

#define BB 16384
#define LL 200
#define DD 100
#define VV 100000
#define CHUNK  25000           // f16 entries per LDS chunk: 50,000 B
#define CI4    3125            // int4 per chunk (25000*2/16)
#define NCHUNK 4               // 4 * 25000 = 100000 = VV exactly
#define FBLK   512             // 2 blocks/CU: 2x50KB LDS + 2x1024 thr = CU caps
#define FTHR   1024            // 16 waves/block; 32 waves/CU total (full TLP)
#define RPW    2               // pool rows per wave: 32 rows/block / 16 waves
#define PAIRS_PER_BLK 98       // 98*512 = 50176 >= 50000 row-pairs

// Fused kernel, take 2. R18 failed because 100KB LDS forced 1 block/CU ->
// phase 1 at half TLP (16 waves/CU). Here: 50KB chunks, 512 blocks = 2/CU,
// grid == device capacity (thread cap 2048/CU enforces exactly 2 resident)
// -> barrier-safe AND phase 1 at full 32 waves/CU.
__global__ __launch_bounds__(1024) void fused_kernel(const int4* __restrict__ idx4,
                                                     const float4* __restrict__ E4,
                                                     const float4* __restrict__ w4,
                                                     __half* __restrict__ rowdot,
                                                     int* __restrict__ bar,
                                                     float* __restrict__ out) {
    __shared__ __half sh[CHUNK];
    const int t    = threadIdx.x;
    const int wv   = t >> 6;                 // wave 0..15
    const int lane = t & 63;
    const int half = lane >> 5;
    const int sub  = lane & 31;
    const bool act = lane < 50;
    const int row0 = blockIdx.x * 32 + wv * RPW;

    // ---- issue pool idx loads FIRST (13MB rides under phase-1's E read)
    int4 pf[RPW];
    #pragma unroll
    for (int r = 0; r < RPW; ++r)
        pf[r] = act ? idx4[(size_t)(row0 + r) * 50 + lane]
                    : make_int4(0, 0, 0, 0);

    // ---- phase 1: rowdot pairs [blk*98, blk*98+98), half-wave per row
    float4 wvf = make_float4(0.f, 0.f, 0.f, 0.f);
    if (sub < 25) wvf = w4[sub];
    const int p0 = blockIdx.x * PAIRS_PER_BLK;
    #pragma unroll 2
    for (int i = wv; i < PAIRS_PER_BLK; i += 16) {
        const int p = p0 + i;
        if (p < VV / 2) {
            const int r = p * 2 + half;
            float s = 0.0f;
            if (sub < 25) {
                float4 v = E4[(size_t)r * 25 + sub];
                s = v.x * wvf.x + v.y * wvf.y + v.z * wvf.z + v.w * wvf.w;
            }
            #pragma unroll
            for (int off = 16; off > 0; off >>= 1)
                s += __shfl_xor(s, off, 64);
            float s1 = __shfl(s, 32, 64);    // UNIFORM exec (R13 lesson)
            if (lane == 0) {
                unsigned u0 = __half_as_ushort(__float2half(s));
                unsigned u1 = __half_as_ushort(__float2half(s1));
                ((unsigned*)rowdot)[p] = u0 | (u1 << 16);
            }
        }
    }

    // ---- device barrier (R18-proven correct): agent-scope release flushes
    // this XCD's L2; acquire invalidates before phase-2 reads.
    __syncthreads();
    if (t == 0) {
        __hip_atomic_fetch_add(bar, 1, __ATOMIC_RELEASE, __HIP_MEMORY_SCOPE_AGENT);
        while (__hip_atomic_load(bar, __ATOMIC_ACQUIRE, __HIP_MEMORY_SCOPE_AGENT) < FBLK)
            __builtin_amdgcn_s_sleep(2);
        __threadfence();
    }
    __syncthreads();

    // ---- phase 2 (R16-proven): async-stage table chunks, probe from LDS
    float acc[RPW] = {0.f, 0.f};
    const int4* src = (const int4*)rowdot;
    #pragma unroll 1
    for (int c = 0; c < NCHUNK; ++c) {
        const int base = c * CHUNK;
        __syncthreads();                      // prev chunk's readers done
        #pragma unroll
        for (int j = 0; j < 4; ++j) {
            const int k = j * FTHR + t;
            if (k < CI4) {
                const int4* gp = src + c * CI4 + k;               // per-lane
                char* lb = (char*)sh + j * 16384 + wv * 1024;     // wave-uniform
                __builtin_amdgcn_global_load_lds(
                    (const __attribute__((address_space(1))) void*)gp,
                    (__attribute__((address_space(3))) void*)lb,
                    16, 0, 0);
            }
        }
        __syncthreads();                      // drain -> staged data visible
        if (act) {
            #pragma unroll
            for (int r = 0; r < RPW; ++r) {
                int4 i4 = pf[r];
                int a0 = i4.x - base, a1 = i4.y - base;
                int a2 = i4.z - base, a3 = i4.w - base;
                if ((unsigned)a0 < (unsigned)CHUNK) acc[r] += __half2float(sh[a0]);
                if ((unsigned)a1 < (unsigned)CHUNK) acc[r] += __half2float(sh[a1]);
                if ((unsigned)a2 < (unsigned)CHUNK) acc[r] += __half2float(sh[a2]);
                if ((unsigned)a3 < (unsigned)CHUNK) acc[r] += __half2float(sh[a3]);
            }
        }
    }

    #pragma unroll
    for (int r = 0; r < RPW; ++r) {
        float s = acc[r];
        #pragma unroll
        for (int off = 32; off > 0; off >>= 1)
            s += __shfl_xor(s, off, 64);
        if (lane == 0) out[row0 + r] = s * (1.0f / LL);
    }
}

extern "C" void kernel_launch(void* const* d_in, const int* in_sizes, int n_in,
                              void* d_out, int out_size, void* d_ws, size_t ws_size,
                              hipStream_t stream) {
    const int4*   idx4   = (const int4*)d_in[0];      // [B, L] int32 as int4
    const float4* E4     = (const float4*)d_in[1];    // [V, D] f32 as float4
    const float4* w4     = (const float4*)d_in[2];    // [D, 1] f32 as float4
    float*        out    = (float*)d_out;             // [B, 1] f32
    __half*       rowdot = (__half*)d_ws;             // 200 KB f16 table
    int*          bar    = (int*)((char*)d_ws + 262144);  // barrier counter

    // counter must be 0 every call (ws poisoned 0xAA once, not re-poisoned)
    hipMemsetAsync(bar, 0, sizeof(int), stream);
    fused_kernel<<<FBLK, FTHR, 0, stream>>>(idx4, E4, w4, rowdot, bar, out);
}

// Round 20
// 22.868 us; speedup vs baseline: 2.8887x; 2.8887x over previous
//
#include <hip/hip_runtime.h>
#include <hip/hip_fp16.h>

#define BB 16384
#define LL 200
#define DD 100
#define VV 100000
#define CHUNK  50000           // f16 entries per LDS chunk: 100,000 B
#define CI4    6250            // int4 per chunk (50000*2/16)
#define NCHUNK 2               // 2 * 50000 = 100000 = VV exactly
#define PBLK   256             // pool blocks: 1/CU (100KB LDS), ALL 256 CUs
#define PTHR   1024            // 16 waves/block
#define RPW    4               // rows per wave: 64 rows/block / 16 waves

// Kernel 1 (R16 math + NT packed store): rowdot[v] = sum_d E[v,d]*w[d], f16.
// Half-wave (32 lanes) per row, lanes 0..24 load one float4 (25 x 16B = row).
// Store: both halves' sums packed to one u32, written NON-TEMPORALLY so the
// table lands clean in L3 instead of dirty in 8 per-XCD L2s (pool's async
// staging then reads L3-clean lines, no cross-XCD dirty service).
__global__ __launch_bounds__(256) void rowdot_kernel(const float4* __restrict__ E4,
                                                     const float4* __restrict__ w4,
                                                     __half* __restrict__ rowdot) {
    const int tid  = blockIdx.x * blockDim.x + threadIdx.x;
    const int wave = tid >> 6;
    const int lane = threadIdx.x & 63;
    const int half = lane >> 5;
    const int sub  = lane & 31;

    float4 wv = make_float4(0.f, 0.f, 0.f, 0.f);
    if (sub < 25) wv = w4[sub];

    const int r = wave * 2 + half;
    float s = 0.0f;
    if (sub < 25) {
        float4 v = E4[(size_t)r * 25 + sub];
        s = v.x * wv.x + v.y * wv.y + v.z * wv.z + v.w * wv.w;
    }
    #pragma unroll
    for (int off = 16; off > 0; off >>= 1)
        s += __shfl_xor(s, off, 64);          // all 32 lanes of each half hold sum

    float s1 = __shfl(s, 32, 64);             // UNIFORM exec (R13 lesson)
    if (lane == 0) {
        unsigned u0 = __half_as_ushort(__float2half(s));   // row r
        unsigned u1 = __half_as_ushort(__float2half(s1));  // row r+1
        __builtin_nontemporal_store(u0 | (u1 << 16),
                                    (unsigned*)rowdot + (r >> 1));
    }
}

// Kernel 2 (R16-exact, proven): LDS-staged f16 gather via async
// global_load_lds (16B). 256 blocks x 1024 threads, 64 rows/block (4/wave);
// lanes 0..49 hold each row's indices in regs.
__global__ __launch_bounds__(1024) void pool_kernel(const int4* __restrict__ idx4,
                                                    const __half* __restrict__ rowdot,
                                                    float* __restrict__ out) {
    __shared__ __half sh[CHUNK];
    const int t    = threadIdx.x;
    const int wv   = t >> 6;                 // wave id 0..15
    const int lane = t & 63;
    const int row0 = blockIdx.x * 64 + wv * RPW;
    const bool act = lane < 50;

    // preload indices first (coalesced int4, overlaps staging below)
    int4 pf[RPW];
    #pragma unroll
    for (int r = 0; r < RPW; ++r)
        pf[r] = act ? idx4[(size_t)(row0 + r) * 50 + lane]
                    : make_int4(0, 0, 0, 0);

    float acc[RPW] = {0.f, 0.f, 0.f, 0.f};
    const int4* src = (const int4*)rowdot;

    #pragma unroll 1
    for (int c = 0; c < NCHUNK; ++c) {
        const int base = c * CHUNK;
        __syncthreads();   // previous chunk's readers done before overwrite
        #pragma unroll
        for (int j = 0; j < 7; ++j) {
            const int k = j * PTHR + t;
            if (k < CI4) {
                const int4* gp = src + c * CI4 + k;                 // per-lane
                char* lb = (char*)sh + j * 16384 + wv * 1024;       // wave-uniform
                __builtin_amdgcn_global_load_lds(
                    (const __attribute__((address_space(1))) void*)gp,
                    (__attribute__((address_space(3))) void*)lb,
                    16, 0, 0);
            }
        }
        __syncthreads();   // drains vmcnt -> staged data visible in LDS
        if (act) {
            #pragma unroll
            for (int r = 0; r < RPW; ++r) {
                int4 i4 = pf[r];
                int a0 = i4.x - base, a1 = i4.y - base;
                int a2 = i4.z - base, a3 = i4.w - base;
                if ((unsigned)a0 < (unsigned)CHUNK) acc[r] += __half2float(sh[a0]);
                if ((unsigned)a1 < (unsigned)CHUNK) acc[r] += __half2float(sh[a1]);
                if ((unsigned)a2 < (unsigned)CHUNK) acc[r] += __half2float(sh[a2]);
                if ((unsigned)a3 < (unsigned)CHUNK) acc[r] += __half2float(sh[a3]);
            }
        }
    }

    #pragma unroll
    for (int r = 0; r < RPW; ++r) {
        float s = acc[r];
        #pragma unroll
        for (int off = 32; off > 0; off >>= 1)
            s += __shfl_xor(s, off, 64);
        if (lane == 0) out[row0 + r] = s * (1.0f / LL);
    }
}

extern "C" void kernel_launch(void* const* d_in, const int* in_sizes, int n_in,
                              void* d_out, int out_size, void* d_ws, size_t ws_size,
                              hipStream_t stream) {
    const int4*   idx4   = (const int4*)d_in[0];      // [B, L] int32 as int4
    const float4* E4     = (const float4*)d_in[1];    // [V, D] f32 as float4
    const float4* w4     = (const float4*)d_in[2];    // [D, 1] f32 as float4
    float*        out    = (float*)d_out;             // [B, 1] f32
    __half*       rowdot = (__half*)d_ws;             // 200 KB f16 table

    // 100000 rows, 2 rows/wave, 4 waves/block -> 12500 blocks
    rowdot_kernel<<<VV / 8, 256, 0, stream>>>(E4, w4, rowdot);
    // 16384 rows / 64 rows per block -> 256 blocks of 1024 threads
    pool_kernel<<<PBLK, PTHR, 0, stream>>>(idx4, rowdot, out);
}

// Round 21
// 22.042 us; speedup vs baseline: 2.9969x; 1.0374x over previous
//
#include <hip/hip_runtime.h>
#include <hip/hip_fp16.h>

#define BB 16384
#define LL 200
#define DD 100
#define VV 100000
#define CHUNK  50000           // f16 entries per LDS chunk: 100,000 B
#define CI4    6250            // int4 per chunk (50000*2/16)
#define NCHUNK 2               // 2 * 50000 = 100000 = VV exactly
#define PBLK   256             // pool blocks: 1/CU (100KB LDS), ALL 256 CUs
#define PTHR   1024            // 16 waves/block
#define RPW    4               // rows per wave: 64 rows/block / 16 waves

// Kernel 1 (R16 math, packed store, NO cache hints): rowdot[v] = sum_d E[v,d]*w[d].
// Half-wave (32 lanes) per row, lanes 0..24 load one float4 (25 x 16B = row).
// Both halves' sums packed into one u32 store (plain store: R15/R20 showed
// nontemporal REGRESSES — dirty-L2 table lines actually help pool staging).
__global__ __launch_bounds__(256) void rowdot_kernel(const float4* __restrict__ E4,
                                                     const float4* __restrict__ w4,
                                                     __half* __restrict__ rowdot) {
    const int tid  = blockIdx.x * blockDim.x + threadIdx.x;
    const int wave = tid >> 6;
    const int lane = threadIdx.x & 63;
    const int half = lane >> 5;
    const int sub  = lane & 31;

    float4 wv = make_float4(0.f, 0.f, 0.f, 0.f);
    if (sub < 25) wv = w4[sub];

    const int r = wave * 2 + half;
    float s = 0.0f;
    if (sub < 25) {
        float4 v = E4[(size_t)r * 25 + sub];
        s = v.x * wv.x + v.y * wv.y + v.z * wv.z + v.w * wv.w;
    }
    #pragma unroll
    for (int off = 16; off > 0; off >>= 1)
        s += __shfl_xor(s, off, 64);          // all 32 lanes of each half hold sum

    float s1 = __shfl(s, 32, 64);             // UNIFORM exec (R13 lesson)
    if (lane == 0) {
        unsigned u0 = __half_as_ushort(__float2half(s));   // row r
        unsigned u1 = __half_as_ushort(__float2half(s1));  // row r+1
        ((unsigned*)rowdot)[r >> 1] = u0 | (u1 << 16);
    }
}

// Kernel 2 (R16-exact, proven 21.8us): LDS-staged f16 gather via async
// global_load_lds (16B). 256 blocks x 1024 threads, 64 rows/block (4/wave);
// lanes 0..49 hold each row's indices in regs. Staging: ~7 async DMA issues
// per thread back-to-back (no VGPR round-trip, single drain at the barrier).
__global__ __launch_bounds__(1024) void pool_kernel(const int4* __restrict__ idx4,
                                                    const __half* __restrict__ rowdot,
                                                    float* __restrict__ out) {
    __shared__ __half sh[CHUNK];
    const int t    = threadIdx.x;
    const int wv   = t >> 6;                 // wave id 0..15
    const int lane = t & 63;
    const int row0 = blockIdx.x * 64 + wv * RPW;
    const bool act = lane < 50;

    // preload indices first (coalesced int4, overlaps staging below)
    int4 pf[RPW];
    #pragma unroll
    for (int r = 0; r < RPW; ++r)
        pf[r] = act ? idx4[(size_t)(row0 + r) * 50 + lane]
                    : make_int4(0, 0, 0, 0);

    float acc[RPW] = {0.f, 0.f, 0.f, 0.f};
    const int4* src = (const int4*)rowdot;

    #pragma unroll 1
    for (int c = 0; c < NCHUNK; ++c) {
        const int base = c * CHUNK;
        __syncthreads();   // previous chunk's readers done before overwrite
        #pragma unroll
        for (int j = 0; j < 7; ++j) {
            const int k = j * PTHR + t;
            if (k < CI4) {
                const int4* gp = src + c * CI4 + k;                 // per-lane
                char* lb = (char*)sh + j * 16384 + wv * 1024;       // wave-uniform
                __builtin_amdgcn_global_load_lds(
                    (const __attribute__((address_space(1))) void*)gp,
                    (__attribute__((address_space(3))) void*)lb,
                    16, 0, 0);
            }
        }
        __syncthreads();   // drains vmcnt -> staged data visible in LDS
        if (act) {
            #pragma unroll
            for (int r = 0; r < RPW; ++r) {
                int4 i4 = pf[r];
                int a0 = i4.x - base, a1 = i4.y - base;
                int a2 = i4.z - base, a3 = i4.w - base;
                if ((unsigned)a0 < (unsigned)CHUNK) acc[r] += __half2float(sh[a0]);
                if ((unsigned)a1 < (unsigned)CHUNK) acc[r] += __half2float(sh[a1]);
                if ((unsigned)a2 < (unsigned)CHUNK) acc[r] += __half2float(sh[a2]);
                if ((unsigned)a3 < (unsigned)CHUNK) acc[r] += __half2float(sh[a3]);
            }
        }
    }

    #pragma unroll
    for (int r = 0; r < RPW; ++r) {
        float s = acc[r];
        #pragma unroll
        for (int off = 32; off > 0; off >>= 1)
            s += __shfl_xor(s, off, 64);
        if (lane == 0) out[row0 + r] = s * (1.0f / LL);
    }
}

extern "C" void kernel_launch(void* const* d_in, const int* in_sizes, int n_in,
                              void* d_out, int out_size, void* d_ws, size_t ws_size,
                              hipStream_t stream) {
    const int4*   idx4   = (const int4*)d_in[0];      // [B, L] int32 as int4
    const float4* E4     = (const float4*)d_in[1];    // [V, D] f32 as float4
    const float4* w4     = (const float4*)d_in[2];    // [D, 1] f32 as float4
    float*        out    = (float*)d_out;             // [B, 1] f32
    __half*       rowdot = (__half*)d_ws;             // 200 KB f16 table

    // 100000 rows, 2 rows/wave, 4 waves/block -> 12500 blocks
    rowdot_kernel<<<VV / 8, 256, 0, stream>>>(E4, w4, rowdot);
    // 16384 rows / 64 rows per block -> 256 blocks of 1024 threads
    pool_kernel<<<PBLK, PTHR, 0, stream>>>(idx4, rowdot, out);
}